// Round 5
// baseline (781.166 us; speedup 1.0000x reference)
//
#include <hip/hip_runtime.h>
#include <hip/hip_bf16.h>

// irreps: 128x0e + 128x1o + 128x2e ; N=100000 nodes, IN_DIM=OUT_DIM=1152
// out[z, off_b + w*d + i] = alpha * sum_u W_b[u,w] * x[z, off_b + u*d + i]
// alpha = 1/sqrt(128) for all three blocks.

#define N_NODES 100000
#define IN_DIM  1152
#define ZT      32                    // nodes per workgroup
#define NWG     (N_NODES / ZT)        // 3125, exact
#define THREADS 512

typedef __attribute__((ext_vector_type(8))) short bf16x8;   // 8 bf16 (4 VGPRs)
typedef __attribute__((ext_vector_type(4))) float f32x4;

__device__ __forceinline__ unsigned short f2bf(float x) {
    // round-to-nearest-even fp32 -> bf16 (inputs are finite random normals)
    unsigned int u = __float_as_uint(x);
    unsigned int r = (u + 0x7FFFu + ((u >> 16) & 1u)) >> 16;
    return (unsigned short)r;
}

// ---------------------------------------------------------------------------
// Prep: weight fp32 [b][u][w] -> bf16 image [b][w][u] * alpha, stored in the
// XOR-swizzled layout (byte ^= (row&7)<<4 within each 256B row) so the main
// kernel can copy it linearly into LDS and read swizzled (rule: both sides).
// ---------------------------------------------------------------------------
__global__ void prep_w_kernel(const float* __restrict__ w, unsigned int* __restrict__ wimg) {
    int t = blockIdx.x * 256 + threadIdx.x;       // one 4-byte pair each
    if (t >= 3 * 8192) return;
    int b = t >> 13;                               // block id
    int p = t & 8191;                              // pair within block
    int A = p * 4;                                 // image byte addr in block
    int row = A >> 8;                              // w index (0..127)
    int P = A ^ ((row & 7) << 4);                  // plain byte addr
    int u0 = (P & 255) >> 1;                       // even
    const float alpha = 0.08838834764831845f;      // 1/sqrt(128)
    float v0 = w[b * 16384 + (u0    ) * 128 + row] * alpha;
    float v1 = w[b * 16384 + (u0 + 1) * 128 + row] * alpha;
    unsigned int pack = (unsigned int)f2bf(v0) | ((unsigned int)f2bf(v1) << 16);
    wimg[t] = pack;                                // byte addr b*32768 + A
}

// ---------------------------------------------------------------------------
// Main kernel: one WG = 32 nodes, 3 sequential block phases (d = 1,3,5).
// LDS: [0,32768) = W_b as bf16 [w][u] swizzled; [32768, 73728) = A tile
// bf16 [r][u] swizzled, r = i*32 + z_local (up to 160 rows).
// 8 waves; wave w owns output cols n in [w*16, w*16+16).
// ---------------------------------------------------------------------------
template <int D>
__device__ __forceinline__ void run_block(const float* __restrict__ x,
                                          const unsigned int* __restrict__ wimg,
                                          float* __restrict__ out,
                                          char* smem, int tid, int zbase,
                                          int off, int wb) {
    __syncthreads();   // previous phase finished reading LDS

    // ---- stage W: 32 KB linear copy of pre-swizzled image (L2-resident) ----
    {
        const uint4* src = reinterpret_cast<const uint4*>(wimg) + wb * 2048;
        uint4* dst = reinterpret_cast<uint4*>(smem);
#pragma unroll
        for (int it = 0; it < 4; ++it)
            dst[it * THREADS + tid] = src[it * THREADS + tid];
    }

    // ---- stage A: 32 nodes x 128*D fp32 -> bf16 LDS, coalesced float4 ----
    {
        char* a_lds = smem + 32768;
        const float4* src4 = reinterpret_cast<const float4*>(x);
#pragma unroll
        for (int it = 0; it < 2 * D; ++it) {
            int e4 = it * THREADS + tid;           // float4 index in tile
            int e = e4 * 4;                        // element index in tile
            int z = e / (128 * D);
            int rem = e - z * (128 * D);
            float4 v = src4[((zbase + z) * IN_DIM + off + rem) >> 2];
            if (D == 1) {
                // rem = u0 (multiple of 4), i = 0, r = z: pack 4 bf16 -> b64
                int r = z;
                int byte = (r * 256 + rem * 2) ^ ((r & 7) << 4);
                unsigned int lo = (unsigned int)f2bf(v.x) | ((unsigned int)f2bf(v.y) << 16);
                unsigned int hi = (unsigned int)f2bf(v.z) | ((unsigned int)f2bf(v.w) << 16);
                uint2 pk; pk.x = lo; pk.y = hi;
                *reinterpret_cast<uint2*>(a_lds + byte) = pk;
            } else {
                float vv[4] = {v.x, v.y, v.z, v.w};
#pragma unroll
                for (int j = 0; j < 4; ++j) {
                    int rj = rem + j;
                    int u = rj / D;
                    int i = rj - u * D;
                    int r = i * 32 + z;
                    int byte = (r * 256 + u * 2) ^ ((r & 7) << 4);
                    *reinterpret_cast<unsigned short*>(a_lds + byte) = f2bf(vv[j]);
                }
            }
        }
    }
    __syncthreads();

    // ---- MFMA: M = 32*D rows, N = 16 cols per wave, K = 128 ----
    const int lane = tid & 63;
    const int wave = tid >> 6;
    const int n0 = wave * 16;
    const int lrow = lane & 15;
    const int lkb = (lane >> 4) * 16;              // k-block byte offset
    constexpr int MT = 2 * D;
    f32x4 acc[MT];
#pragma unroll
    for (int m = 0; m < MT; ++m) acc[m] = (f32x4){0.f, 0.f, 0.f, 0.f};

    char* a_lds = smem + 32768;
#pragma unroll
    for (int ks = 0; ks < 4; ++ks) {
        int wrow = n0 + lrow;
        int wbyte = (wrow * 256 + ks * 64 + lkb) ^ ((wrow & 7) << 4);
        bf16x8 bfrag = *reinterpret_cast<bf16x8*>(smem + wbyte);
#pragma unroll
        for (int mt = 0; mt < MT; ++mt) {
            int ar = mt * 16 + lrow;
            int abyte = (ar * 256 + ks * 64 + lkb) ^ ((ar & 7) << 4);
            bf16x8 afrag = *reinterpret_cast<bf16x8*>(a_lds + abyte);
            acc[mt] = __builtin_amdgcn_mfma_f32_16x16x32_bf16(afrag, bfrag, acc[mt], 0, 0, 0);
        }
    }

    // ---- epilogue: C[r][n] -> out[zbase+z, off + n*D + i], r = i*32+z ----
    const int wcol = n0 + lrow;                    // output w index
#pragma unroll
    for (int mt = 0; mt < MT; ++mt) {
#pragma unroll
        for (int j = 0; j < 4; ++j) {
            int r = mt * 16 + (lane >> 4) * 4 + j;
            int z = r & 31;
            int i = r >> 5;
            out[(zbase + z) * IN_DIM + off + wcol * D + i] = acc[mt][j];
        }
    }
}

__global__ __launch_bounds__(THREADS, 4)
void linear_e3nn_kernel(const float* __restrict__ x,
                        const unsigned int* __restrict__ wimg,
                        float* __restrict__ out) {
    __shared__ __align__(16) char smem[32768 + 40960];
    const int tid = threadIdx.x;
    const int zbase = blockIdx.x * ZT;
    run_block<1>(x, wimg, out, smem, tid, zbase, 0,   0);
    run_block<3>(x, wimg, out, smem, tid, zbase, 128, 1);
    run_block<5>(x, wimg, out, smem, tid, zbase, 512, 2);
}

extern "C" void kernel_launch(void* const* d_in, const int* in_sizes, int n_in,
                              void* d_out, int out_size, void* d_ws, size_t ws_size,
                              hipStream_t stream) {
    const float* features = (const float*)d_in[0];   // [100000, 1152] fp32
    const float* weight   = (const float*)d_in[1];   // [49152] fp32
    float* out = (float*)d_out;                      // [100000, 1152] fp32
    unsigned int* wimg = (unsigned int*)d_ws;        // 98304 B bf16 weight image

    prep_w_kernel<<<96, 256, 0, stream>>>(weight, wimg);
    linear_e3nn_kernel<<<NWG, THREADS, 0, stream>>>(features, wimg, out);
}

// Round 6
// 779.000 us; speedup vs baseline: 1.0028x; 1.0028x over previous
//
#include <hip/hip_runtime.h>
#include <hip/hip_bf16.h>

// irreps: 128x0e + 128x1o + 128x2e ; N=100000 nodes, IN_DIM=OUT_DIM=1152
// out[z, off_b + w*d + i] = alpha * sum_u W_b[u,w] * x[z, off_b + u*d + i]
// alpha = 1/sqrt(128). Pipelined: W frags in regs, A double-buffered in LDS,
// cross-phase register prefetch (T14), 3 barriers per WG.

#define N_NODES 100000
#define IN_DIM  1152
#define ZT      32                    // nodes per workgroup
#define NWG     (N_NODES / ZT)        // 3125, exact
#define THREADS 512

typedef __attribute__((ext_vector_type(8))) short bf16x8;   // 8 bf16 (4 VGPRs)
typedef __attribute__((ext_vector_type(4))) float f32x4;

__device__ __forceinline__ unsigned short f2bf(float x) {
    // round-to-nearest-even fp32 -> bf16
    unsigned int u = __float_as_uint(x);
    unsigned int r = (u + 0x7FFFu + ((u >> 16) & 1u)) >> 16;
    return (unsigned short)r;
}

// ---------------------------------------------------------------------------
// Prep: weight fp32 [b][u][w] -> bf16 fragment-direct image * alpha.
// Fragment (b, wave, ks, lane) = 8 bf16: alpha*W[u0+j][wrow], j=0..7,
// wrow = wave*16 + (lane&15), u0 = ks*32 + (lane>>4)*8.
// Image uint4 index = ((b*8+wave)*4+ks)*64 + lane  -> main kernel loads are
// 16 B/lane fully coalesced, L2-resident (96 KB total).
// ---------------------------------------------------------------------------
__global__ void prep_w_kernel(const float* __restrict__ w, uint4* __restrict__ wimg) {
    int t = blockIdx.x * 256 + threadIdx.x;        // 6144 fragments
    if (t >= 6144) return;
    int b   = t >> 11;
    int r   = t & 2047;
    int wv  = r >> 8;
    int r2  = r & 255;
    int ks  = r2 >> 6;
    int l   = r2 & 63;
    int wrow = wv * 16 + (l & 15);
    int u0   = ks * 32 + (l >> 4) * 8;
    const float alpha = 0.08838834764831845f;      // 1/sqrt(128)
    unsigned int pk[4];
#pragma unroll
    for (int j2 = 0; j2 < 4; ++j2) {
        float v0 = w[b * 16384 + (u0 + 2 * j2    ) * 128 + wrow] * alpha;
        float v1 = w[b * 16384 + (u0 + 2 * j2 + 1) * 128 + wrow] * alpha;
        pk[j2] = (unsigned int)f2bf(v0) | ((unsigned int)f2bf(v1) << 16);
    }
    uint4 o; o.x = pk[0]; o.y = pk[1]; o.z = pk[2]; o.w = pk[3];
    wimg[t] = o;
}

// ---------------------------------------------------------------------------
// Main kernel helpers
// ---------------------------------------------------------------------------
template <int D>
__device__ __forceinline__ void issue_loads(const float* __restrict__ x, int tid,
                                            int zbase, int off, float4 (&p)[2 * D]) {
    const float4* src4 = reinterpret_cast<const float4*>(x);
#pragma unroll
    for (int it = 0; it < 2 * D; ++it) {
        int e4 = it * THREADS + tid;
        int e = e4 * 4;
        int z = e / (128 * D);
        int rem = e - z * (128 * D);
        p[it] = src4[((zbase + z) * IN_DIM + off + rem) >> 2];
    }
}

// Convert prefetched fp32 regs -> bf16, scatter into swizzled A-LDS tile.
// Layout: row r = i*32 + z (256 B bf16[128] per row), byte ^= (r&7)<<4.
template <int D>
__device__ __forceinline__ void stage_tile(char* a_lds, int tid, const float4 (&p)[2 * D]) {
#pragma unroll
    for (int it = 0; it < 2 * D; ++it) {
        int e4 = it * THREADS + tid;
        int e = e4 * 4;
        int z = e / (128 * D);
        int rem = e - z * (128 * D);
        float4 v = p[it];
        if (D == 1) {
            int r = z;
            int byte = (r * 256 + rem * 2) ^ ((r & 7) << 4);
            unsigned int lo = (unsigned int)f2bf(v.x) | ((unsigned int)f2bf(v.y) << 16);
            unsigned int hi = (unsigned int)f2bf(v.z) | ((unsigned int)f2bf(v.w) << 16);
            uint2 pk; pk.x = lo; pk.y = hi;
            *reinterpret_cast<uint2*>(a_lds + byte) = pk;
        } else {
            float vv[4] = {v.x, v.y, v.z, v.w};
#pragma unroll
            for (int j = 0; j < 4; ++j) {
                int rj = rem + j;
                int u = rj / D;
                int i = rj - u * D;
                int r = i * 32 + z;
                int byte = (r * 256 + u * 2) ^ ((r & 7) << 4);
                *reinterpret_cast<unsigned short*>(a_lds + byte) = f2bf(vv[j]);
            }
        }
    }
}

__device__ __forceinline__ void load_w(const uint4* __restrict__ wimg, int b,
                                       int wave, int lane, bf16x8 (&wf)[4]) {
#pragma unroll
    for (int ks = 0; ks < 4; ++ks) {
        uint4 u = wimg[((b * 8 + wave) * 4 + ks) * 64 + lane];
        wf[ks] = *reinterpret_cast<bf16x8*>(&u);
    }
}

// MFMA over the staged tile + scattered epilogue store (math identical to the
// verified r5 kernel; C/D map: col=lane&15, row=(lane>>4)*4+reg  [m89]).
template <int D>
__device__ __forceinline__ void compute_store(const char* a_lds, const bf16x8 (&wf)[4],
                                              float* __restrict__ out, int zbase,
                                              int off, int lane, int wave) {
    const int n0 = wave * 16;
    const int lrow = lane & 15;
    const int lkb = (lane >> 4) * 16;
    constexpr int MT = 2 * D;
    f32x4 acc[MT];
#pragma unroll
    for (int m = 0; m < MT; ++m) acc[m] = (f32x4){0.f, 0.f, 0.f, 0.f};

#pragma unroll
    for (int ks = 0; ks < 4; ++ks) {
#pragma unroll
        for (int mt = 0; mt < MT; ++mt) {
            int ar = mt * 16 + lrow;
            int abyte = (ar * 256 + ks * 64 + lkb) ^ ((ar & 7) << 4);
            bf16x8 afrag = *reinterpret_cast<const bf16x8*>(a_lds + abyte);
            acc[mt] = __builtin_amdgcn_mfma_f32_16x16x32_bf16(afrag, wf[ks], acc[mt], 0, 0, 0);
        }
    }

    const int wcol = n0 + lrow;
#pragma unroll
    for (int mt = 0; mt < MT; ++mt) {
#pragma unroll
        for (int j = 0; j < 4; ++j) {
            int r = mt * 16 + (lane >> 4) * 4 + j;
            int z = r & 31;
            int i = r >> 5;
            out[(zbase + z) * IN_DIM + off + wcol * D + i] = acc[mt][j];
        }
    }
}

// ---------------------------------------------------------------------------
// Pipeline per WG (3 barriers):
//   issue P0,P1 -> stage0(buf0) -> sync
//   [issue P2] compute0(buf0,W0) -> stage1(buf1) -> sync
//   compute1(buf1,W1) -> stage2(buf0) -> sync      (buf0 readers done at sync2)
//   compute2(buf0,W2)
// ---------------------------------------------------------------------------
__global__ __launch_bounds__(THREADS, 4)
void linear_e3nn_kernel(const float* __restrict__ x,
                        const uint4* __restrict__ wimg,
                        float* __restrict__ out) {
    __shared__ __align__(16) char smem[2 * 40960];   // A double buffer
    char* buf0 = smem;
    char* buf1 = smem + 40960;
    const int tid = threadIdx.x;
    const int lane = tid & 63;
    const int wave = tid >> 6;
    const int zbase = blockIdx.x * ZT;

    // prefetch phase-0 (D=1) and phase-1 (D=3) tiles into registers
    float4 p0[2];  issue_loads<1>(x, tid, zbase, 0,   p0);
    float4 p1[6];  issue_loads<3>(x, tid, zbase, 128, p1);
    bf16x8 w0[4];  load_w(wimg, 0, wave, lane, w0);

    stage_tile<1>(buf0, tid, p0);
    __syncthreads();

    // phase 0 (D=1) — overlap: issue phase-2 loads + W1 before compute
    float4 p2[10]; issue_loads<5>(x, tid, zbase, 512, p2);
    bf16x8 w1[4];  load_w(wimg, 1, wave, lane, w1);
    compute_store<1>(buf0, w0, out, zbase, 0, lane, wave);
    stage_tile<3>(buf1, tid, p1);
    __syncthreads();

    // phase 1 (D=3)
    bf16x8 w2[4];  load_w(wimg, 2, wave, lane, w2);
    compute_store<3>(buf1, w1, out, zbase, 128, lane, wave);
    stage_tile<5>(buf0, tid, p2);      // buf0 phase-0 reads completed before sync #2
    __syncthreads();

    // phase 2 (D=5)
    compute_store<5>(buf0, w2, out, zbase, 512, lane, wave);
}

extern "C" void kernel_launch(void* const* d_in, const int* in_sizes, int n_in,
                              void* d_out, int out_size, void* d_ws, size_t ws_size,
                              hipStream_t stream) {
    const float* features = (const float*)d_in[0];   // [100000, 1152] fp32
    const float* weight   = (const float*)d_in[1];   // [49152] fp32
    float* out = (float*)d_out;                      // [100000, 1152] fp32
    uint4* wimg = (uint4*)d_ws;                      // 98304 B bf16 fragment image

    prep_w_kernel<<<24, 256, 0, stream>>>(weight, wimg);
    linear_e3nn_kernel<<<NWG, THREADS, 0, stream>>>(features, wimg, out);
}